// Round 15
// baseline (110.250 us; speedup 1.0000x reference)
//
#include <hip/hip_runtime.h>
#include <math.h>

#define NU 512
#define NCH 8192
#define CPB 32              // chains per block -> 256 blocks = 1 wave on every CU
#define NBLK 256
#define PF 8                // ring depth (iterations of 4 steps)

typedef int i4 __attribute__((ext_vector_type(4)));

// R15 = R14 (compile-fixed: iter lambda -> macro; generic-lambda if-constexpr
// capture bug). Free-running single-wave pipeline on ALL 256 CUs, 32 chains
// per block, line-exact 256B dword loads (2 rows x 32 chains), partner rows
// via 2-ahead ds_bpermute (lane^32), 2 line-exact stores/iter.
// vmcnt = exact #ops issued after target batch (per iter: 2 stores + 4 loads):
//   ramp 24,26,28,30,32,34,36,36; steady 36; tail 36,32,28,24,20,16,12.
__device__ __forceinline__ i4 mksrd(const void* p) {
    i4 v;
    v.x = (int)(unsigned)(uintptr_t)p;
    v.y = (int)((unsigned)((uintptr_t)p >> 32) & 0xFFFFu);
    v.z = (int)0xFFFFFFFFu;        // bounds check off
    v.w = 0x00020000;              // raw dword SRD
    return v;
}

__global__ __launch_bounds__(64, 1)
void reshopf_kernel(const float* __restrict__ Xr, const float* __restrict__ Xi,
                    const float* __restrict__ r0, const float* __restrict__ phi0,
                    const float* __restrict__ omegas,
                    float* __restrict__ zr, float* __restrict__ r_f,
                    float* __restrict__ phi_f)
{
    const int lane  = (int)threadIdx.x;
    const int ch    = lane & 31;
    const int cbase = (int)blockIdx.x * CPB;
    const int gch   = cbase + ch;
    const bool lo   = lane < 32;

    const float INV2PI = 0.15915494309189533577f;
    const float wo    = omegas[gch & (NU - 1)];
    const float sig   = 1.0f / (1.0f + __expf(-wo));
    const float a_rev = (sig * 19.5f + 0.5f) * 0.01f;     // om*dt, revolutions
    const float Ca    = __builtin_amdgcn_cosf(a_rev);
    const float Sa    = __builtin_amdgcn_sinf(a_rev);

    float r        = r0[gch];
    const float p0 = phi0[gch];
    float si = __builtin_amdgcn_sinf(p0 * INV2PI);
    float co = __builtin_amdgcn_cosf(p0 * INV2PI);
    float acc = 0.0f;

    const i4 srdR = mksrd(Xr + cbase);
    const i4 srdI = mksrd(Xi + cbase);
    const i4 srdZ = mksrd(zr + cbase);
    // lane -> (row parity lane>>5, chain lane&31): one dword inst = 2 rows x 32 ch
    //       = two 128B-aligned 128B segments (line-exact, zero waste)
    const unsigned voff = ((unsigned)(lane >> 5)) * 32768u + (unsigned)ch * 4u;
    const unsigned vxa  = (unsigned)((lane ^ 32) << 2);   // bpermute partner addr

    // ring: slot s (= iter & 7) holds rows {4i + par, 4i+2 + par}, par = lane>>5
    float gR0[PF], gR1[PF], gI0[PF], gI1[PF];
    // bperm result sets (alternate by iter parity): partner's two rows
    float paR1, paR3, paI1, paI3;
    float pbR1, pbR3, pbI1, pbI3;

#define LD1(dst, srd, so) asm volatile("buffer_load_dword %0, %1, %2, %3 offen" \
        : "=v"(dst) : "v"(voff), "s"(srd), "s"(so))
#define LOADS(S, it) { const unsigned s0_ = (unsigned)(4 * (it)) * 32768u; \
        LD1(gR0[S], srdR, s0_); LD1(gR1[S], srdR, s0_ + 65536u); \
        LD1(gI0[S], srdI, s0_); LD1(gI1[S], srdI, s0_ + 65536u); }

#define BPERM(S, X) { \
        asm volatile("ds_bpermute_b32 %0, %1, %2" : "=v"(X##R1) : "v"(vxa), "v"(gR0[S])); \
        asm volatile("ds_bpermute_b32 %0, %1, %2" : "=v"(X##R3) : "v"(vxa), "v"(gR1[S])); \
        asm volatile("ds_bpermute_b32 %0, %1, %2" : "=v"(X##I1) : "v"(vxa), "v"(gI0[S])); \
        asm volatile("ds_bpermute_b32 %0, %1, %2" : "=v"(X##I3) : "v"(vxa), "v"(gI1[S])); }

    auto step = [&](float xr, float xi, float& zout) {
        const float kxi = xi * -0.05f;
        const float kxr = xr * 0.05f;
        const float eps = kxi * si;
        const float t1  = si * Ca;
        const float sA  = fmaf(co, Sa, t1);               // sin(phi+a)
        const float t2  = co * Ca;
        const float cA  = fmaf(-si, Sa, t2);              // cos(phi+a)
        const float rr  = r * r;
        const float g1  = fmaf(-rr, r, r);                // (1-r^2)*r
        const float tr  = fmaf(kxr, co, r);               // uses OLD cos
        r  = fmaf(0.01f, g1, tr);
        si = fmaf(eps, cA, sA);                           // first-order rot(eps)
        co = fmaf(-eps, sA, cA);
        acc += eps;
        zout = r * co;
    };

#define CONSUME(S, X, it) { \
        const float xr0 = lo ? gR0[S] : X##R1; \
        const float xr1 = lo ? X##R1 : gR0[S]; \
        const float xr2 = lo ? gR1[S] : X##R3; \
        const float xr3 = lo ? X##R3 : gR1[S]; \
        const float xi0 = lo ? gI0[S] : X##I1; \
        const float xi1 = lo ? X##I1 : gI0[S]; \
        const float xi2 = lo ? gI1[S] : X##I3; \
        const float xi3 = lo ? X##I3 : gI1[S]; \
        float z0_, z1_, z2_, z3_; \
        step(xr0, xi0, z0_); step(xr1, xi1, z1_); \
        step(xr2, xi2, z2_); step(xr3, xi3, z3_); \
        const float m_ = fmaf(si, si, co * co); \
        const float n_ = fmaf(-0.5f, m_, 1.5f); \
        si *= n_; co *= n_; \
        const float zA = lo ? z0_ : z1_; \
        const float zB = lo ? z2_ : z3_; \
        const unsigned so_ = (unsigned)(4 * (it)) * 32768u; \
        asm volatile("buffer_store_dword %0, %1, %2, %3 offen" \
            :: "v"(zA), "v"(voff), "s"(srdZ), "s"(so_) : "memory"); \
        asm volatile("buffer_store_dword %0, %1, %2, %3 offen" \
            :: "v"(zB), "v"(voff), "s"(srdZ), "s"(so_ + 65536u) : "memory"); }

    // iter body: WAITVM(NW) -> bperm slot NS into BSET -> lgkm(4) (prev bperms
    // done) -> consume slot S from CSET (4 steps + 2 stores) -> REFILL
#define ITER(S, NS, NW, BSET, CSET, it, REFILL) { \
        asm volatile("s_waitcnt vmcnt(%0)" :: "n"(NW) : "memory"); \
        __builtin_amdgcn_sched_barrier(0); \
        BPERM(NS, BSET) \
        asm volatile("s_waitcnt lgkmcnt(4)" ::: "memory"); \
        __builtin_amdgcn_sched_barrier(0); \
        CONSUME(S, CSET, it) \
        REFILL }

    // prologue: fill ring (32 loads), bperm slot 0 into set pa
    LOADS(0, 0) LOADS(1, 1) LOADS(2, 2) LOADS(3, 3)
    LOADS(4, 4) LOADS(5, 5) LOADS(6, 6) LOADS(7, 7)
    asm volatile("s_waitcnt vmcnt(28)" ::: "memory");   // slot 0 done
    __builtin_amdgcn_sched_barrier(0);
    BPERM(0, pa)

    // ramp i=0..7
    ITER(0, 1, 24, pb, pa, 0, LOADS(0, 8))
    ITER(1, 2, 26, pa, pb, 1, LOADS(1, 9))
    ITER(2, 3, 28, pb, pa, 2, LOADS(2, 10))
    ITER(3, 4, 30, pa, pb, 3, LOADS(3, 11))
    ITER(4, 5, 32, pb, pa, 4, LOADS(4, 12))
    ITER(5, 6, 34, pa, pb, 5, LOADS(5, 13))
    ITER(6, 7, 36, pb, pa, 6, LOADS(6, 14))
    ITER(7, 0, 36, pa, pb, 7, LOADS(7, 15))

    // steady: i=8..503 (62 blocks of 8), uniform vmcnt(36)
    for (int b = 0; b < 62; ++b) {
        const int ib = 8 + b * 8;
        ITER(0, 1, 36, pb, pa, ib + 0, LOADS(0, ib + 8))
        ITER(1, 2, 36, pa, pb, ib + 1, LOADS(1, ib + 9))
        ITER(2, 3, 36, pb, pa, ib + 2, LOADS(2, ib + 10))
        ITER(3, 4, 36, pa, pb, ib + 3, LOADS(3, ib + 11))
        ITER(4, 5, 36, pb, pa, ib + 4, LOADS(4, ib + 12))
        ITER(5, 6, 36, pa, pb, ib + 5, LOADS(5, ib + 13))
        ITER(6, 7, 36, pb, pa, ib + 6, LOADS(6, ib + 14))
        ITER(7, 0, 36, pa, pb, ib + 7, LOADS(7, ib + 15))
    }

    // tail i=504..510 (no refills; exact ops-after-target ramp-down)
    ITER(0, 1, 36, pb, pa, 504, ((void)0);)
    ITER(1, 2, 32, pa, pb, 505, ((void)0);)
    ITER(2, 3, 28, pb, pa, 506, ((void)0);)
    ITER(3, 4, 24, pa, pb, 507, ((void)0);)
    ITER(4, 5, 20, pb, pa, 508, ((void)0);)
    ITER(5, 6, 16, pa, pb, 509, ((void)0);)
    ITER(6, 7, 12, pb, pa, 510, ((void)0);)
    // final i=511: slot 7, set pb (bperm'd at i=510); no loads left
    asm volatile("s_waitcnt lgkmcnt(0)" ::: "memory");
    __builtin_amdgcn_sched_barrier(0);
    CONSUME(7, pb, 511)

    if (lo) {
        r_f[gch] = r;
        phi_f[gch] = (float)((double)p0
                     + (double)a_rev * 2048.0 * 6.283185307179586476925287
                     + (double)acc);
    }
}

extern "C" void kernel_launch(void* const* d_in, const int* in_sizes, int n_in,
                              void* d_out, int out_size, void* d_ws, size_t ws_size,
                              hipStream_t stream) {
    const float* Xr   = (const float*)d_in[0];
    const float* Xi   = (const float*)d_in[1];
    const float* r0   = (const float*)d_in[2];
    const float* phi0 = (const float*)d_in[3];
    const float* om   = (const float*)d_in[4];

    float* out   = (float*)d_out;
    float* zrp   = out;                               // Re(z): T*NCH floats
    float* r_f   = out + (size_t)2048 * NCH;          // NCH floats
    float* phi_f = r_f + NCH;                         // NCH floats

    reshopf_kernel<<<NBLK, 64, 0, stream>>>(Xr, Xi, r0, phi0, om, zrp, r_f, phi_f);
}

// Round 16
// 98.146 us; speedup vs baseline: 1.1233x; 1.1233x over previous
//
#include <hip/hip_runtime.h>
#include <math.h>

#define NU 512
#define NCH 8192
#define CPB 32              // chains per block
#define NBLK 256            // 1 block/CU (96KB LDS)

typedef int i4 __attribute__((ext_vector_type(4)));
typedef float f2 __attribute__((ext_vector_type(2)));
typedef float f4 __attribute__((ext_vector_type(4)));

// R16 = R13 (best: 98.6us) + bijective XCD-aware block swizzle:
//   sbid = (bid&7)*32 + (bid>>3)  (bijective: 256 % 8 == 0)
// Default dispatch puts block b on XCD b%8; under the swizzle each XCD owns a
// CONTIGUOUS 1024-chain (4KB-per-row) panel instead of scattered 128B slices.
// Theory: 9 structures all plateau at ~1.3 TB/s because stride-32KB 128B-
// granular per-XCD streams are DRAM row-activate-bound; 4KB-dense per-XCD
// spans let the memory controller merge page hits. Everything else verbatim R13.
__device__ __forceinline__ i4 mksrd(const void* p) {
    i4 v;
    v.x = (int)(unsigned)(uintptr_t)p;
    v.y = (int)((unsigned)((uintptr_t)p >> 32) & 0xFFFFu);
    v.z = (int)0xFFFFFFFFu;        // bounds check off
    v.w = 0x00020000;              // raw dword SRD
    return v;
}

__global__ __launch_bounds__(320, 1)
void reshopf_kernel(const float* __restrict__ Xr, const float* __restrict__ Xi,
                    const float* __restrict__ r0, const float* __restrict__ phi0,
                    const float* __restrict__ omegas,
                    float* __restrict__ zr, float* __restrict__ r_f,
                    float* __restrict__ phi_f)
{
    __shared__ float lds[24576];   // [R in: 0..32KB) [I in: 32..64KB) [z: 64..96KB)
    const int tid   = (int)threadIdx.x;
    const int lane  = tid & 63;
    const int wid   = __builtin_amdgcn_readfirstlane(tid >> 6);   // 0..4, uniform
    const int bid   = (int)blockIdx.x;
    const int sbid  = ((bid & 7) << 5) | (bid >> 3);   // XCD-contiguous panels
    const int cbase = sbid * CPB;
    const unsigned ldsb = (unsigned)(uintptr_t)&lds[0];

    if (wid < 4) {
        // ===================== LSU waves (verbatim R13) =====================
        const unsigned voff = ((unsigned)(lane >> 3)) * 32768u
                            + ((unsigned)(lane & 7)) * 16u;
        const i4 srdR = mksrd(Xr + cbase);
        const i4 srdI = mksrd(Xi + cbase);
        const i4 srdZ = mksrd(zr + cbase);
        const unsigned wl = ldsb + (unsigned)wid * 4096u
                          + ((unsigned)(lane >> 3)) * 128u
                          + ((unsigned)(lane & 7)) * 16u;

        f4 aR[4], aI[4], bR[4], bI[4], zv[4];   // static-indexed only

#define LD4(dst, srd, so) asm volatile("buffer_load_dwordx4 %0, %1, %2, %3 offen" \
        : "=v"(dst) : "v"(voff), "s"(srd), "s"(so))
#define LOADS(X, baseRow) { \
        const unsigned s0_ = ((unsigned)(baseRow) + (unsigned)wid * 32u) * 32768u; \
        LD4(X##R[0], srdR, s0_);            LD4(X##R[1], srdR, s0_ + 262144u); \
        LD4(X##R[2], srdR, s0_ + 524288u);  LD4(X##R[3], srdR, s0_ + 786432u); \
        LD4(X##I[0], srdI, s0_);            LD4(X##I[1], srdI, s0_ + 262144u); \
        LD4(X##I[2], srdI, s0_ + 524288u);  LD4(X##I[3], srdI, s0_ + 786432u); }

#define WRITES(X, HP) { const unsigned a_ = wl + (HP); \
        asm volatile("ds_write_b128 %0, %1 offset:0"     :: "v"(a_), "v"(X##R[0])); \
        asm volatile("ds_write_b128 %0, %1 offset:1024"  :: "v"(a_), "v"(X##R[1])); \
        asm volatile("ds_write_b128 %0, %1 offset:2048"  :: "v"(a_), "v"(X##R[2])); \
        asm volatile("ds_write_b128 %0, %1 offset:3072"  :: "v"(a_), "v"(X##R[3])); \
        asm volatile("ds_write_b128 %0, %1 offset:32768" :: "v"(a_), "v"(X##I[0])); \
        asm volatile("ds_write_b128 %0, %1 offset:33792" :: "v"(a_), "v"(X##I[1])); \
        asm volatile("ds_write_b128 %0, %1 offset:34816" :: "v"(a_), "v"(X##I[2])); \
        asm volatile("ds_write_b128 %0, %1 offset:35840" :: "v"(a_), "v"(X##I[3])); }

#define ZREADS(HP) { const unsigned a_ = wl + 65536u + (HP); \
        asm volatile("ds_read_b128 %0, %1 offset:0"    : "=v"(zv[0]) : "v"(a_)); \
        asm volatile("ds_read_b128 %0, %1 offset:1024" : "=v"(zv[1]) : "v"(a_)); \
        asm volatile("ds_read_b128 %0, %1 offset:2048" : "=v"(zv[2]) : "v"(a_)); \
        asm volatile("ds_read_b128 %0, %1 offset:3072" : "=v"(zv[3]) : "v"(a_)); }

#define ZSTORES(baseRow) { \
        const unsigned s0_ = ((unsigned)(baseRow) + (unsigned)wid * 32u) * 32768u; \
        asm volatile("buffer_store_dwordx4 %0, %1, %2, %3 offen" \
            :: "v"(zv[0]), "v"(voff), "s"(srdZ), "s"(s0_) : "memory"); \
        asm volatile("buffer_store_dwordx4 %0, %1, %2, %3 offen" \
            :: "v"(zv[1]), "v"(voff), "s"(srdZ), "s"(s0_ + 262144u) : "memory"); \
        asm volatile("buffer_store_dwordx4 %0, %1, %2, %3 offen" \
            :: "v"(zv[2]), "v"(voff), "s"(srdZ), "s"(s0_ + 524288u) : "memory"); \
        asm volatile("buffer_store_dwordx4 %0, %1, %2, %3 offen" \
            :: "v"(zv[3]), "v"(voff), "s"(srdZ), "s"(s0_ + 786432u) : "memory"); }

#define WAITVM(N) asm volatile("s_waitcnt vmcnt(%0)" :: "n"(N) : "memory")
#define WAITLG    asm volatile("s_waitcnt lgkmcnt(0)" ::: "memory")
#define WAITEX    asm volatile("s_waitcnt expcnt(0)" ::: "memory")

        // P(-2): pre-issue BOTH halves
        LOADS(a, 0);
        LOADS(b, 128);
        __builtin_amdgcn_s_barrier();                              // #1
        WAITVM(8);
        WRITES(a, 0u);
        WAITLG;
        __builtin_amdgcn_s_barrier();                              // #2

        // phase 0
        WAITVM(0);
        WRITES(b, 16384u);
        LOADS(a, 256);
        WAITLG;
        __builtin_amdgcn_s_barrier();                              // #3
        // phase 1
        WAITVM(0);
        WRITES(a, 0u);
        LOADS(b, 384);
        WAITEX;
        ZREADS(0u);
        WAITLG;
        ZSTORES(0);
        __builtin_amdgcn_s_barrier();                              // #4
        // phases 2..13
        for (int pp = 1; pp < 7; ++pp) {
            WAITVM(4);
            WRITES(b, 16384u);
            LOADS(a, (2 * pp + 2) * 128);
            WAITEX;
            ZREADS(16384u);
            WAITLG;
            ZSTORES((2 * pp - 1) * 128);
            __builtin_amdgcn_s_barrier();
            WAITVM(4);
            WRITES(a, 0u);
            LOADS(b, (2 * pp + 3) * 128);
            WAITEX;
            ZREADS(0u);
            WAITLG;
            ZSTORES((2 * pp) * 128);
            __builtin_amdgcn_s_barrier();
        }
        // phase 14
        WAITVM(4);
        WRITES(b, 16384u);
        WAITEX;
        ZREADS(16384u);
        WAITLG;
        ZSTORES(13 * 128);
        __builtin_amdgcn_s_barrier();                              // #17
        // phase 15
        WAITEX;
        ZREADS(0u);
        WAITLG;
        ZSTORES(14 * 128);
        __builtin_amdgcn_s_barrier();                              // #18
        // post
        WAITEX;
        ZREADS(16384u);
        WAITLG;
        ZSTORES(15 * 128);
    } else {
        // ===================== compute wave (verbatim R13) =====================
        const int l   = lane & 31;            // lanes 32-63 duplicate 0-31
        const int gch = cbase + l;
        const float INV2PI = 0.15915494309189533577f;

        const float wo    = omegas[gch & (NU - 1)];
        const float sig   = 1.0f / (1.0f + __expf(-wo));
        const float a_rev = (sig * 19.5f + 0.5f) * 0.01f;
        const float Ca    = __builtin_amdgcn_cosf(a_rev);
        const float Sa    = __builtin_amdgcn_sinf(a_rev);

        float r        = r0[gch];
        const float p0 = phi0[gch];
        float s = __builtin_amdgcn_sinf(p0 * INV2PI);
        float c = __builtin_amdgcn_cosf(p0 * INV2PI);
        float acc = 0.0f;

        const unsigned vR = ldsb + (unsigned)l * 4u;
        const unsigned vI = vR + 32768u;
        const unsigned vZ = vR + 65536u;

        auto step = [&](float xr, float xi, float& zout) {
            const float kxi = xi * -0.05f;
            const float kxr = xr * 0.05f;
            const float eps = kxi * s;
            const float t1  = s * Ca;
            const float sA  = fmaf(c, Sa, t1);
            const float t2  = c * Ca;
            const float cA  = fmaf(-s, Sa, t2);
            const float rr  = r * r;
            const float g1  = fmaf(-rr, r, r);
            const float tr  = fmaf(kxr, c, r);
            r = fmaf(0.01f, g1, tr);
            s = fmaf(eps, cA, sA);
            c = fmaf(-eps, sA, cA);
            acc += eps;
            zout = r * c;
        };

        // 4 rotating input sets (static names; no runtime indexing)
        f2 S0r01, S0r23, S0i01, S0i23;
        f2 S1r01, S1r23, S1i01, S1i23;
        f2 S2r01, S2r23, S2i01, S2i23;
        f2 S3r01, S3r23, S3i01, S3i23;

#define RDs(it, S) { \
        const unsigned so_ = ((unsigned)((it) & 63)) * 512u; \
        const unsigned aR_ = vR + so_, aI_ = vI + so_; \
        asm volatile("ds_read2_b32 %0, %1 offset0:0 offset1:32"  : "=v"(S##r01) : "v"(aR_)); \
        asm volatile("ds_read2_b32 %0, %1 offset0:64 offset1:96" : "=v"(S##r23) : "v"(aR_)); \
        asm volatile("ds_read2_b32 %0, %1 offset0:0 offset1:32"  : "=v"(S##i01) : "v"(aI_)); \
        asm volatile("ds_read2_b32 %0, %1 offset0:64 offset1:96" : "=v"(S##i23) : "v"(aI_)); }

#define COMPs(it, S) { \
        float z0_, z1_, z2_, z3_; \
        step(S##r01.x, S##i01.x, z0_); step(S##r01.y, S##i01.y, z1_); \
        step(S##r23.x, S##i23.x, z2_); step(S##r23.y, S##i23.y, z3_); \
        const float m_ = fmaf(s, s, c * c); \
        const float n_ = fmaf(-0.5f, m_, 1.5f); \
        s *= n_; c *= n_; \
        const unsigned aZ_ = vZ + ((unsigned)((it) & 63)) * 512u; \
        asm volatile("ds_write2_b32 %0, %1, %2 offset0:0 offset1:32"  :: "v"(aZ_), "v"(z0_), "v"(z1_)); \
        asm volatile("ds_write2_b32 %0, %1, %2 offset0:64 offset1:96" :: "v"(aZ_), "v"(z2_), "v"(z3_)); }

#define WL(N) { asm volatile("s_waitcnt lgkmcnt(%0)" :: "n"(N) : "memory"); \
                __builtin_amdgcn_sched_barrier(0); }

        __builtin_amdgcn_s_barrier();                              // #1
        __builtin_amdgcn_s_barrier();                              // #2  (half0 sealed)

        for (int p = 0; p < 16; ++p) {
            const int s0 = p * 32;
            // prologue: 2 slots ahead (both within this sealed half)
            RDs(s0 + 0, S0); RDs(s0 + 1, S1);
            // k=0,1 (ramp waits: exact ops-after-target counts)
            RDs(s0 + 2, S2); WL(8);  COMPs(s0 + 0, S0);
            RDs(s0 + 3, S3); WL(10); COMPs(s0 + 1, S1);
            // k=2..29: steady, wait targets reads issued 2 iters ago
            for (int g = 0; g < 7; ++g) {
                const int k = s0 + 2 + g * 4;
                RDs(k + 2, S0); WL(12); COMPs(k + 0, S2);
                RDs(k + 3, S1); WL(12); COMPs(k + 1, S3);
                RDs(k + 4, S2); WL(12); COMPs(k + 2, S0);
                RDs(k + 5, S3); WL(12); COMPs(k + 3, S1);
            }
            // k=30,31: no more reads (look-ahead clamped at half boundary)
            WL(8); COMPs(s0 + 30, S2);
            WL(4); COMPs(s0 + 31, S3);
            asm volatile("s_waitcnt lgkmcnt(0)" ::: "memory");     // z writes sealed
            __builtin_amdgcn_s_barrier();                          // #3..#18
        }

        if (lane < 32) {
            r_f[gch] = r;
            phi_f[gch] = (float)((double)p0
                         + (double)a_rev * 2048.0 * 6.283185307179586476925287
                         + (double)acc);
        }
    }
}

extern "C" void kernel_launch(void* const* d_in, const int* in_sizes, int n_in,
                              void* d_out, int out_size, void* d_ws, size_t ws_size,
                              hipStream_t stream) {
    const float* Xr   = (const float*)d_in[0];
    const float* Xi   = (const float*)d_in[1];
    const float* r0   = (const float*)d_in[2];
    const float* phi0 = (const float*)d_in[3];
    const float* om   = (const float*)d_in[4];

    float* out   = (float*)d_out;
    float* zrp   = out;                               // Re(z): T*NCH floats
    float* r_f   = out + (size_t)2048 * NCH;          // NCH floats
    float* phi_f = r_f + NCH;                         // NCH floats

    reshopf_kernel<<<NBLK, 320, 0, stream>>>(Xr, Xi, r0, phi0, om, zrp, r_f, phi_f);
}